// Round 8
// baseline (685.930 us; speedup 1.0000x reference)
//
#include <hip/hip_runtime.h>
#include <hip/hip_cooperative_groups.h>

namespace cg = cooperative_groups;

// ---------------- problem constants ----------------
constexpr int N_NODES  = 50000;
constexpr int N_EDGES  = 800000;
constexpr int N_GRAPHS = 512;
constexpr int F_IN     = 128;
constexpr int HID      = 256;
constexpr int NPAD     = 50048;   // 391*128
constexpr int PBLK     = 512;     // cooperative prep grid (2 blocks/CU, register-light)
constexpr int SPAN     = 98;      // nodes per block in scan phases (512*98 = 50176)

typedef short short8 __attribute__((ext_vector_type(8)));
typedef float f32x4  __attribute__((ext_vector_type(4)));

// bf16 helpers (raw ushort storage; RNE rounding)
__device__ __forceinline__ unsigned short f2b(float f) {
    unsigned u = __float_as_uint(f);
    u += 0x7fffu + ((u >> 16) & 1u);
    return (unsigned short)(u >> 16);
}
__device__ __forceinline__ float b2f_lo(unsigned u) { return __uint_as_float(u << 16); }
__device__ __forceinline__ float b2f_hi(unsigned u) { return __uint_as_float(u & 0xffff0000u); }

// inclusive scan of 256 ints in LDS; afterwards sm holds the full inclusive scan
__device__ __forceinline__ int lds_scan_incl(int* sm, int v) {
    const int t = threadIdx.x;
    sm[t] = v; __syncthreads();
    #pragma unroll
    for (int o = 1; o < 256; o <<= 1) {
        int a = (t >= o) ? sm[t - o] : 0; __syncthreads();
        sm[t] += a; __syncthreads();
    }
    return sm[t];
}

// ---------------- cooperative prep: zero+conv+wt -> deg -> dis+bsum -> scan -> fill_csr ----------------
__global__ __launch_bounds__(256, 2) void prep_all(
    const int* __restrict__ src, const int* __restrict__ dst,
    const float* __restrict__ x,
    const float* __restrict__ W0, const float* __restrict__ W1, const float* __restrict__ W2,
    int* deg, float* dis, int* row_start, int* cursor, int* bsum, unsigned* csr,
    unsigned short* x_bf, unsigned short* Wt0, unsigned short* Wt1, unsigned short* Wt2)
{
    __shared__ int sm[256];
    cg::grid_group grid = cg::this_grid();
    const int t   = threadIdx.x;
    const int b   = blockIdx.x;
    const int gid = b * 256 + t;
    const int gstride = PBLK * 256;   // 131072

    // ---- P0: zero deg; x fp32->bf16; weight transpose Wt[n][k] ----
    for (int i = gid; i < N_NODES; i += gstride) deg[i] = 0;
    for (int i = gid; i < N_NODES * F_IN / 4; i += gstride) {
        float4 v = *reinterpret_cast<const float4*>(x + (size_t)i * 4);
        unsigned r0 = (unsigned)f2b(v.x) | ((unsigned)f2b(v.y) << 16);
        unsigned r1 = (unsigned)f2b(v.z) | ((unsigned)f2b(v.w) << 16);
        *reinterpret_cast<uint2*>(x_bf + (size_t)i * 4) = make_uint2(r0, r1);
    }
    for (int i = gid; i < 163840; i += gstride) {
        const float* W; unsigned short* Wt; int K, j;
        if (i < 32768)      { W = W0; Wt = Wt0; K = 128; j = i; }
        else if (i < 98304) { W = W1; Wt = Wt1; K = 256; j = i - 32768; }
        else                { W = W2; Wt = Wt2; K = 256; j = i - 98304; }
        int k = j >> 8, n = j & 255;
        Wt[n * K + k] = f2b(W[j]);
    }
    grid.sync();

    // ---- P1: degree histogram ----
    for (int e = gid; e < N_EDGES; e += gstride) atomicAdd(&deg[dst[e]], 1);
    grid.sync();

    // ---- P2: dis + per-block degree sums over SPAN-node spans ----
    {
        int node = b * SPAN + t;
        int d = 0;
        if (t < SPAN && node < N_NODES) { d = deg[node]; dis[node] = rsqrtf((float)d + 1.0f); }
        sm[t] = d; __syncthreads();
        #pragma unroll
        for (int o = 128; o > 0; o >>= 1) { if (t < o) sm[t] += sm[t + o]; __syncthreads(); }
        if (t == 0) bsum[b] = sm[0];
    }
    grid.sync();

    // ---- P3: global exclusive scan -> row_start, cursor ----
    {
        // pair-compress 512 block sums into 256, scan in LDS
        int pv = bsum[2 * t] + bsum[2 * t + 1];
        lds_scan_incl(sm, pv);                  // sm = inclusive scan of pair sums
        const int p = b >> 1;
        int Pb = (p > 0) ? sm[p - 1] : 0;
        if (b & 1) Pb += bsum[2 * p];
        const int grand = sm[255];
        __syncthreads();
        int node = b * SPAN + t;
        int v = (t < SPAN && node < N_NODES) ? deg[node] : 0;
        int incl = lds_scan_incl(sm, v);
        int excl = incl - v + Pb;
        if (t < SPAN && node < N_NODES) { row_start[node] = excl; cursor[node] = excl; }
        if (b == PBLK - 1 && t == 0) row_start[N_NODES] = grand;   // == N_EDGES
    }
    grid.sync();

    // ---- P4: CSR fill: 4B entry = (bf16 w << 16) | u16 src ----
    for (int e = gid; e < N_EDGES; e += gstride) {
        int s = src[e], d = dst[e];
        int pos = atomicAdd(&cursor[d], 1);
        float w = dis[s] * dis[d];
        csr[pos] = ((unsigned)f2b(w) << 16) | (unsigned)s;
    }
}

// ---------------- aggregation (R3-verified structure, 4B csr): bf16 in/out, fp32 accumulate ----------------
template<int K>
__global__ __launch_bounds__(256) void agg_bf16(
    const unsigned short* __restrict__ hin, const int* __restrict__ row_start,
    const unsigned* __restrict__ csr, const float* __restrict__ dis,
    unsigned short* __restrict__ out)
{
    constexpr int LPR  = K / 8;     // lanes per row: 32 (K=256) / 16 (K=128)
    constexpr int NSUB = 64 / LPR;  // subgroups per wave
    const int lane = threadIdx.x & 63;
    const int sub  = lane / LPR;
    const int fc   = lane % LPR;
    const int node = blockIdx.x * 4 + (threadIdx.x >> 6);
    if (node >= N_NODES) return;

    float acc[8];
    {   // self-loop (sub 0 only contributes)
        float dn = dis[node];
        float sw = (sub == 0) ? dn * dn : 0.0f;
        uint2 u2[2];
        *reinterpret_cast<uint4*>(u2) =
            *reinterpret_cast<const uint4*>(hin + (size_t)node * K + fc * 8);
        #pragma unroll
        for (int h = 0; h < 2; ++h) {
            acc[h * 4 + 0] = b2f_lo(u2[h].x) * sw;
            acc[h * 4 + 1] = b2f_hi(u2[h].x) * sw;
            acc[h * 4 + 2] = b2f_lo(u2[h].y) * sw;
            acc[h * 4 + 3] = b2f_hi(u2[h].y) * sw;
        }
    }

    int j = row_start[node] + sub;
    const int end = row_start[node + 1];
    for (; j + 3 * NSUB < end; j += 4 * NSUB) {
        unsigned c[4];
        #pragma unroll
        for (int u = 0; u < 4; ++u) c[u] = csr[j + u * NSUB];
        #pragma unroll
        for (int u = 0; u < 4; ++u) {
            float w = b2f_hi(c[u]);
            uint2 g[2];
            *reinterpret_cast<uint4*>(g) =
                *reinterpret_cast<const uint4*>(hin + (size_t)(c[u] & 0xffffu) * K + fc * 8);
            #pragma unroll
            for (int h = 0; h < 2; ++h) {
                acc[h * 4 + 0] = fmaf(b2f_lo(g[h].x), w, acc[h * 4 + 0]);
                acc[h * 4 + 1] = fmaf(b2f_hi(g[h].x), w, acc[h * 4 + 1]);
                acc[h * 4 + 2] = fmaf(b2f_lo(g[h].y), w, acc[h * 4 + 2]);
                acc[h * 4 + 3] = fmaf(b2f_hi(g[h].y), w, acc[h * 4 + 3]);
            }
        }
    }
    for (; j < end; j += NSUB) {
        unsigned c0 = csr[j];
        float w = b2f_hi(c0);
        uint2 g[2];
        *reinterpret_cast<uint4*>(g) =
            *reinterpret_cast<const uint4*>(hin + (size_t)(c0 & 0xffffu) * K + fc * 8);
        #pragma unroll
        for (int h = 0; h < 2; ++h) {
            acc[h * 4 + 0] = fmaf(b2f_lo(g[h].x), w, acc[h * 4 + 0]);
            acc[h * 4 + 1] = fmaf(b2f_hi(g[h].x), w, acc[h * 4 + 1]);
            acc[h * 4 + 2] = fmaf(b2f_lo(g[h].y), w, acc[h * 4 + 2]);
            acc[h * 4 + 3] = fmaf(b2f_hi(g[h].y), w, acc[h * 4 + 3]);
        }
    }

    #pragma unroll
    for (int k = 0; k < 8; ++k) {
        #pragma unroll
        for (int off = LPR; off < 64; off <<= 1)
            acc[k] += __shfl_xor(acc[k], off, 64);
    }

    if (sub == 0) {
        uint2 rv[2];
        #pragma unroll
        for (int h = 0; h < 2; ++h) {
            rv[h].x = (unsigned)f2b(acc[h * 4 + 0]) | ((unsigned)f2b(acc[h * 4 + 1]) << 16);
            rv[h].y = (unsigned)f2b(acc[h * 4 + 2]) | ((unsigned)f2b(acc[h * 4 + 3]) << 16);
        }
        *reinterpret_cast<uint4*>(out + (size_t)node * K + fc * 8) =
            *reinterpret_cast<uint4*>(rv);
    }
}

// ---------------- bf16 MFMA GEMM (R3-verified): C[NPAD,256] = A @ Wt^T + bias, ReLU ----------------
template<int K>
__global__ __launch_bounds__(256) void gemm_mfma(
    const unsigned short* __restrict__ A,
    const unsigned short* __restrict__ Bt,
    const float* __restrict__ bias,
    unsigned short* __restrict__ C,
    int relu)
{
    __shared__ __align__(16) unsigned short As[2][4 * 128 * 8];
    __shared__ __align__(16) unsigned short Bs[2][4 * 128 * 8];
    const int t    = threadIdx.x;
    const int lane = t & 63;
    const int w    = t >> 6;
    const int wm   = w & 1, wn = w >> 1;
    const int q    = lane >> 4, m = lane & 15;
    const int row0 = blockIdx.x * 128;
    const int col0 = blockIdx.y * 128;
    const int r_   = t >> 2, c_ = t & 3;

    f32x4 acc[4][4] = {};

    auto stage = [&](int buf, int k0) {
        #pragma unroll
        for (int pass = 0; pass < 2; ++pass) {
            int r = r_ + pass * 64;
            uint4 av = *reinterpret_cast<const uint4*>(A  + (size_t)(row0 + r) * K + k0 + c_ * 8);
            uint4 bv = *reinterpret_cast<const uint4*>(Bt + (size_t)(col0 + r) * K + k0 + c_ * 8);
            *reinterpret_cast<uint4*>(&As[buf][(c_ * 128 + r) * 8]) = av;
            *reinterpret_cast<uint4*>(&Bs[buf][(c_ * 128 + r) * 8]) = bv;
        }
    };

    constexpr int NK = K / 32;
    stage(0, 0);
    __syncthreads();
    #pragma unroll
    for (int kb = 0; kb < NK; ++kb) {
        if (kb + 1 < NK) stage((kb + 1) & 1, (kb + 1) * 32);
        const unsigned short* as = As[kb & 1];
        const unsigned short* bs = Bs[kb & 1];
        short8 af[4], bf[4];
        #pragma unroll
        for (int i = 0; i < 4; ++i)
            af[i] = *reinterpret_cast<const short8*>(&as[(q * 128 + wm * 64 + i * 16 + m) * 8]);
        #pragma unroll
        for (int jn = 0; jn < 4; ++jn)
            bf[jn] = *reinterpret_cast<const short8*>(&bs[(q * 128 + wn * 64 + jn * 16 + m) * 8]);
        #pragma unroll
        for (int i = 0; i < 4; ++i)
            #pragma unroll
            for (int jn = 0; jn < 4; ++jn)
                acc[i][jn] = __builtin_amdgcn_mfma_f32_16x16x32_bf16(af[i], bf[jn], acc[i][jn], 0, 0, 0);
        __syncthreads();
    }

    #pragma unroll
    for (int jn = 0; jn < 4; ++jn) {
        int col = col0 + wn * 64 + jn * 16 + m;
        float bj = bias[col];
        #pragma unroll
        for (int i = 0; i < 4; ++i) {
            int rowb = row0 + wm * 64 + i * 16 + q * 4;
            #pragma unroll
            for (int r = 0; r < 4; ++r) {
                float v = acc[i][jn][r] + bj;
                if (relu) v = fmaxf(v, 0.f);
                C[(size_t)(rowb + r) * 256 + col] = f2b(v);
            }
        }
    }
}

// ---------------- fused pool + MLP head ----------------
__global__ __launch_bounds__(256) void pool_mlp_kernel(
    const unsigned short* __restrict__ h, const int* __restrict__ batch,
    const float* __restrict__ Wm1, const float* __restrict__ bm1,
    const float* __restrict__ Wm2, const float* __restrict__ bm2,
    float* __restrict__ out)
{
    __shared__ float p[HID];
    __shared__ float red[HID];
    __shared__ int se[2];
    const int g = blockIdx.x, t = threadIdx.x;
    if (t < 2) {
        int target = g + t;
        int lo = 0, hi = N_NODES;
        while (lo < hi) { int mid = (lo + hi) >> 1; if (batch[mid] < target) lo = mid + 1; else hi = mid; }
        se[t] = lo;
    }
    __syncthreads();
    const int s = se[0], e = se[1];
    float acc = 0.f;
    for (int n = s; n < e; ++n) acc += b2f_lo((unsigned)h[(size_t)n * HID + t]);
    p[t] = acc / fmaxf((float)(e - s), 1.0f);
    __syncthreads();
    float a2 = bm1[t];
    for (int k = 0; k < HID; ++k) a2 = fmaf(p[k], Wm1[k * HID + t], a2);
    red[t] = fmaxf(a2, 0.f) * Wm2[t];
    __syncthreads();
    for (int o = 128; o > 0; o >>= 1) {
        if (t < o) red[t] += red[t + o];
        __syncthreads();
    }
    if (t == 0) out[g] = red[0] + bm2[0];
}

// ---------------- launch ----------------
extern "C" void kernel_launch(void* const* d_in, const int* in_sizes, int n_in,
                              void* d_out, int out_size, void* d_ws, size_t ws_size,
                              hipStream_t stream) {
    const float* x    = (const float*)d_in[0];
    const int*   ei   = (const int*)d_in[1];
    const int*   batch= (const int*)d_in[2];
    const float* W0   = (const float*)d_in[3];
    const float* b0   = (const float*)d_in[4];
    const float* W1   = (const float*)d_in[5];
    const float* b1   = (const float*)d_in[6];
    const float* W2   = (const float*)d_in[7];
    const float* b2   = (const float*)d_in[8];
    const float* Wm1  = (const float*)d_in[9];
    const float* bm1  = (const float*)d_in[10];
    const float* Wm2  = (const float*)d_in[11];
    const float* bm2  = (const float*)d_in[12];
    float* out = (float*)d_out;

    char* ws = (char*)d_ws;
    size_t off = 0;
    auto alloc = [&](size_t bytes) -> void* {
        void* p = ws + off;
        off += (bytes + 255) & ~(size_t)255;
        return p;
    };
    int*      deg       = (int*)     alloc((size_t)N_NODES * 4);
    float*    dis       = (float*)   alloc((size_t)N_NODES * 4);
    int*      row_start = (int*)     alloc((size_t)(N_NODES + 1) * 4);
    int*      cursor    = (int*)     alloc((size_t)N_NODES * 4);
    int*      bsum      = (int*)     alloc((size_t)PBLK * 4);
    unsigned* csr       = (unsigned*)alloc((size_t)N_EDGES * 4);
    unsigned short* x_bf = (unsigned short*)alloc((size_t)N_NODES * F_IN * 2);
    unsigned short* Wt0  = (unsigned short*)alloc((size_t)F_IN * HID * 2);
    unsigned short* Wt1  = (unsigned short*)alloc((size_t)HID * HID * 2);
    unsigned short* Wt2  = (unsigned short*)alloc((size_t)HID * HID * 2);
    unsigned short* bufA = (unsigned short*)alloc((size_t)NPAD * HID * 2);
    unsigned short* h1   = (unsigned short*)alloc((size_t)NPAD * HID * 2);
    unsigned short* h2   = (unsigned short*)alloc((size_t)NPAD * HID * 2);

    const int* srcp = ei;
    const int* dstp = ei + N_EDGES;

    void* pargs[] = {
        (void*)&srcp, (void*)&dstp, (void*)&x,
        (void*)&W0, (void*)&W1, (void*)&W2,
        (void*)&deg, (void*)&dis, (void*)&row_start, (void*)&cursor, (void*)&bsum, (void*)&csr,
        (void*)&x_bf, (void*)&Wt0, (void*)&Wt1, (void*)&Wt2
    };
    hipLaunchCooperativeKernel((void*)prep_all, dim3(PBLK), dim3(256), pargs, 0, stream);

    dim3 ggrid(NPAD / 128, 2);

    agg_bf16<F_IN><<<(N_NODES + 3) / 4, 256, 0, stream>>>(x_bf, row_start, csr, dis, bufA);
    gemm_mfma<F_IN><<<ggrid, 256, 0, stream>>>(bufA, Wt0, b0, h1, 1);

    agg_bf16<HID><<<(N_NODES + 3) / 4, 256, 0, stream>>>(h1, row_start, csr, dis, bufA);
    gemm_mfma<HID><<<ggrid, 256, 0, stream>>>(bufA, Wt1, b1, h2, 1);

    agg_bf16<HID><<<(N_NODES + 3) / 4, 256, 0, stream>>>(h2, row_start, csr, dis, bufA);
    gemm_mfma<HID><<<ggrid, 256, 0, stream>>>(bufA, Wt2, b2, h1, 1);

    pool_mlp_kernel<<<N_GRAPHS, 256, 0, stream>>>(h1, batch, Wm1, bm1, Wm2, bm2, out);
}

// Round 9
// 434.992 us; speedup vs baseline: 1.5769x; 1.5769x over previous
//
#include <hip/hip_runtime.h>

// ---------------- problem constants ----------------
constexpr int N_NODES  = 50000;
constexpr int N_EDGES  = 800000;
constexpr int N_GRAPHS = 512;
constexpr int F_IN     = 128;
constexpr int HID      = 256;
constexpr int NPAD     = 50048;   // 391*128

typedef short short8 __attribute__((ext_vector_type(8)));
typedef float f32x4  __attribute__((ext_vector_type(4)));

// bf16 helpers (raw ushort storage; RNE rounding)
__device__ __forceinline__ unsigned short f2b(float f) {
    unsigned u = __float_as_uint(f);
    u += 0x7fffu + ((u >> 16) & 1u);
    return (unsigned short)(u >> 16);
}
__device__ __forceinline__ float b2f_lo(unsigned u) { return __uint_as_float(u << 16); }
__device__ __forceinline__ float b2f_hi(unsigned u) { return __uint_as_float(u & 0xffff0000u); }

// ---------------- prep: deg histogram + x->bf16 + weights -> B-fragment layout ----------------
// Wfrag ushort index: half*(K*128) + ((k>>3)*128 + (n&127))*8 + (k&7), half = n>>7  [R4-verified]
__global__ __launch_bounds__(256) void prep_kernel(
    const int* __restrict__ dst, int* __restrict__ deg,
    const float* __restrict__ x, unsigned short* __restrict__ x_bf,
    const float* __restrict__ W0, const float* __restrict__ W1, const float* __restrict__ W2,
    unsigned short* __restrict__ Wt0, unsigned short* __restrict__ Wt1, unsigned short* __restrict__ Wt2)
{
    const int b = blockIdx.x, t = threadIdx.x;
    if (b < 3125) {
        int e = b * 256 + t;                       // 3125*256 == 800000
        atomicAdd(&deg[dst[e]], 1);
    } else if (b < 9375) {
        int i = (b - 3125) * 256 + t;              // 6250*256 == 1.6M float4
        float4 v = *reinterpret_cast<const float4*>(x + (size_t)i * 4);
        unsigned r0 = (unsigned)f2b(v.x) | ((unsigned)f2b(v.y) << 16);
        unsigned r1 = (unsigned)f2b(v.z) | ((unsigned)f2b(v.w) << 16);
        *reinterpret_cast<uint2*>(x_bf + (size_t)i * 4) = make_uint2(r0, r1);
    } else {
        int i = (b - 9375) * 256 + t;              // 640*256 == 163840
        const float* W; unsigned short* Wt; int K; int j;
        if (i < 32768)      { W = W0; Wt = Wt0; K = 128; j = i; }
        else if (i < 98304) { W = W1; Wt = Wt1; K = 256; j = i - 32768; }
        else                { W = W2; Wt = Wt2; K = 256; j = i - 98304; }
        int k = j >> 8, n = j & 255;
        int idx = (n >> 7) * (K * 128) + (((k >> 3) * 128 + (n & 127)) << 3) + (k & 7);
        Wt[idx] = f2b(W[j]);
    }
}

// ---------------- single-dispatch scan: dis + exclusive prefix via decoupled lookback ----------------
// 49 blocks x 256 threads, 1024 nodes/block (all blocks co-resident: no forward-progress hazard).
// flags[b]: (state<<30) | value(20b);  state 1=aggregate-ready, 2=prefix-ready. flags pre-zeroed by memset.
__global__ __launch_bounds__(256) void scan_dis_kernel(
    const int* __restrict__ deg, unsigned* flags, float* __restrict__ dis,
    int* __restrict__ row_start, int* __restrict__ cursor)
{
    __shared__ int sm[256];
    __shared__ int Pshare;
    const int t = threadIdx.x, b = blockIdx.x;
    const int base = b * 1024 + t * 4;
    int v[4], s = 0;
    #pragma unroll
    for (int i = 0; i < 4; ++i) {
        int id = base + i;
        int d = (id < N_NODES) ? deg[id] : 0;
        v[i] = d; s += d;
        if (id < N_NODES) dis[id] = rsqrtf((float)d + 1.0f);
    }
    sm[t] = s; __syncthreads();
    #pragma unroll
    for (int o = 1; o < 256; o <<= 1) {
        int a = (t >= o) ? sm[t - o] : 0; __syncthreads();
        sm[t] += a; __syncthreads();
    }
    const int incl = sm[t];
    const int aggB = sm[255];

    if (t == 0) {
        int P = 0;
        if (b == 0) {
            atomicExch(&flags[0], 0x80000000u | (unsigned)aggB);
        } else {
            atomicExch(&flags[b], 0x40000000u | (unsigned)aggB);
            int p = b - 1;
            while (true) {
                unsigned f;
                do { f = atomicAdd(&flags[p], 0u); } while ((f & 0xC0000000u) == 0u);
                P += (int)(f & 0xFFFFFu);
                if (f & 0x80000000u) break;
                --p;
            }
            atomicExch(&flags[b], 0x80000000u | (unsigned)(P + aggB));
        }
        Pshare = P;
        if (b == 48) row_start[N_NODES] = P + aggB;   // == N_EDGES
    }
    __syncthreads();
    int excl = Pshare + incl - s;
    #pragma unroll
    for (int i = 0; i < 4; ++i) {
        int id = base + i;
        if (id < N_NODES) { row_start[id] = excl; cursor[id] = excl; }
        excl += v[i];
    }
}

// ---------------- CSR scatter: 4B entry = (bf16 w << 16) | u16 src ----------------
__global__ void fill_csr(const int* __restrict__ src, const int* __restrict__ dst,
                         const float* __restrict__ dis, int* __restrict__ cursor,
                         unsigned* __restrict__ csr) {
    int e = blockIdx.x * blockDim.x + threadIdx.x;
    if (e >= N_EDGES) return;
    int s = src[e], d = dst[e];
    int pos = atomicAdd(&cursor[d], 1);
    float w = dis[s] * dis[d];
    csr[pos] = ((unsigned)f2b(w) << 16) | (unsigned)s;   // N_NODES < 65536
}

// ---------------- aggregation (R3/R8-verified): bf16 in/out, fp32 accumulate, 4B csr ----------------
template<int K>
__global__ __launch_bounds__(256) void agg_bf16(
    const unsigned short* __restrict__ hin, const int* __restrict__ row_start,
    const unsigned* __restrict__ csr, const float* __restrict__ dis,
    unsigned short* __restrict__ out)
{
    constexpr int LPR  = K / 8;     // lanes per row: 32 (K=256) / 16 (K=128)
    constexpr int NSUB = 64 / LPR;  // subgroups per wave
    const int lane = threadIdx.x & 63;
    const int sub  = lane / LPR;
    const int fc   = lane % LPR;
    const int node = blockIdx.x * 4 + (threadIdx.x >> 6);
    if (node >= N_NODES) return;

    float acc[8];
    {   // self-loop (sub 0 only contributes)
        float dn = dis[node];
        float sw = (sub == 0) ? dn * dn : 0.0f;
        uint2 u2[2];
        *reinterpret_cast<uint4*>(u2) =
            *reinterpret_cast<const uint4*>(hin + (size_t)node * K + fc * 8);
        #pragma unroll
        for (int h = 0; h < 2; ++h) {
            acc[h * 4 + 0] = b2f_lo(u2[h].x) * sw;
            acc[h * 4 + 1] = b2f_hi(u2[h].x) * sw;
            acc[h * 4 + 2] = b2f_lo(u2[h].y) * sw;
            acc[h * 4 + 3] = b2f_hi(u2[h].y) * sw;
        }
    }

    int j = row_start[node] + sub;
    const int end = row_start[node + 1];
    for (; j + 3 * NSUB < end; j += 4 * NSUB) {
        unsigned c[4];
        #pragma unroll
        for (int u = 0; u < 4; ++u) c[u] = csr[j + u * NSUB];
        #pragma unroll
        for (int u = 0; u < 4; ++u) {
            float w = b2f_hi(c[u]);
            uint2 g[2];
            *reinterpret_cast<uint4*>(g) =
                *reinterpret_cast<const uint4*>(hin + (size_t)(c[u] & 0xffffu) * K + fc * 8);
            #pragma unroll
            for (int h = 0; h < 2; ++h) {
                acc[h * 4 + 0] = fmaf(b2f_lo(g[h].x), w, acc[h * 4 + 0]);
                acc[h * 4 + 1] = fmaf(b2f_hi(g[h].x), w, acc[h * 4 + 1]);
                acc[h * 4 + 2] = fmaf(b2f_lo(g[h].y), w, acc[h * 4 + 2]);
                acc[h * 4 + 3] = fmaf(b2f_hi(g[h].y), w, acc[h * 4 + 3]);
            }
        }
    }
    for (; j < end; j += NSUB) {
        unsigned c0 = csr[j];
        float w = b2f_hi(c0);
        uint2 g[2];
        *reinterpret_cast<uint4*>(g) =
            *reinterpret_cast<const uint4*>(hin + (size_t)(c0 & 0xffffu) * K + fc * 8);
        #pragma unroll
        for (int h = 0; h < 2; ++h) {
            acc[h * 4 + 0] = fmaf(b2f_lo(g[h].x), w, acc[h * 4 + 0]);
            acc[h * 4 + 1] = fmaf(b2f_hi(g[h].x), w, acc[h * 4 + 1]);
            acc[h * 4 + 2] = fmaf(b2f_lo(g[h].y), w, acc[h * 4 + 2]);
            acc[h * 4 + 3] = fmaf(b2f_hi(g[h].y), w, acc[h * 4 + 3]);
        }
    }

    #pragma unroll
    for (int k = 0; k < 8; ++k) {
        #pragma unroll
        for (int off = LPR; off < 64; off <<= 1)
            acc[k] += __shfl_xor(acc[k], off, 64);
    }

    if (sub == 0) {
        uint2 rv[2];
        #pragma unroll
        for (int h = 0; h < 2; ++h) {
            rv[h].x = (unsigned)f2b(acc[h * 4 + 0]) | ((unsigned)f2b(acc[h * 4 + 1]) << 16);
            rv[h].y = (unsigned)f2b(acc[h * 4 + 2]) | ((unsigned)f2b(acc[h * 4 + 3]) << 16);
        }
        *reinterpret_cast<uint4*>(out + (size_t)node * K + fc * 8) =
            *reinterpret_cast<uint4*>(rv);
    }
}

// ---------------- barrier-free MFMA GEMM: no LDS, A direct row-major, B direct fragment layout ----------------
// grid (NPAD/128, 2); 256 threads = 4 waves (2x2 of 64x64 within a 128x128 tile).
template<int K>
__global__ __launch_bounds__(256) void gemm_direct(
    const unsigned short* __restrict__ A,       // row-major [NPAD, K]
    const unsigned short* __restrict__ Wfrag,   // [2][K/8][128][8]   (R4-verified layout)
    const float* __restrict__ bias,
    unsigned short* __restrict__ C)             // row-major [NPAD, 256]
{
    const int t    = threadIdx.x;
    const int lane = t & 63;
    const int w    = t >> 6;
    const int wm   = w & 1, wn = w >> 1;
    const int q    = lane >> 4, m = lane & 15;
    const int row0 = blockIdx.x * 128;
    const int half = blockIdx.y;
    const unsigned short* bbase = Wfrag + (size_t)half * (K * 128);

    f32x4 acc[4][4] = {};

    #pragma unroll
    for (int kb = 0; kb < K / 32; ++kb) {
        const int kc = kb * 4 + q;
        short8 af[4], bf[4];
        #pragma unroll
        for (int i = 0; i < 4; ++i)
            af[i] = *reinterpret_cast<const short8*>(
                A + (size_t)(row0 + wm * 64 + i * 16 + m) * K + kc * 8);
        #pragma unroll
        for (int jn = 0; jn < 4; ++jn)
            bf[jn] = *reinterpret_cast<const short8*>(
                bbase + (((size_t)kc * 128 + wn * 64 + jn * 16 + m) << 3));
        #pragma unroll
        for (int i = 0; i < 4; ++i)
            #pragma unroll
            for (int jn = 0; jn < 4; ++jn)
                acc[i][jn] = __builtin_amdgcn_mfma_f32_16x16x32_bf16(af[i], bf[jn], acc[i][jn], 0, 0, 0);
    }

    // epilogue (R3-verified): C/D layout col = lane&15, row = (lane>>4)*4 + reg
    #pragma unroll
    for (int jn = 0; jn < 4; ++jn) {
        int col = half * 128 + wn * 64 + jn * 16 + m;
        float bj = bias[col];
        #pragma unroll
        for (int i = 0; i < 4; ++i) {
            int rowb = row0 + wm * 64 + i * 16 + q * 4;
            #pragma unroll
            for (int r = 0; r < 4; ++r) {
                float v = acc[i][jn][r] + bj;
                v = fmaxf(v, 0.f);
                C[(size_t)(rowb + r) * 256 + col] = f2b(v);
            }
        }
    }
}

// ---------------- fused pool + MLP head ----------------
__global__ __launch_bounds__(256) void pool_mlp_kernel(
    const unsigned short* __restrict__ h, const int* __restrict__ batch,
    const float* __restrict__ Wm1, const float* __restrict__ bm1,
    const float* __restrict__ Wm2, const float* __restrict__ bm2,
    float* __restrict__ out)
{
    __shared__ float p[HID];
    __shared__ float red[HID];
    __shared__ int se[2];
    const int g = blockIdx.x, t = threadIdx.x;
    if (t < 2) {
        int target = g + t;
        int lo = 0, hi = N_NODES;
        while (lo < hi) { int mid = (lo + hi) >> 1; if (batch[mid] < target) lo = mid + 1; else hi = mid; }
        se[t] = lo;
    }
    __syncthreads();
    const int s = se[0], e = se[1];
    float acc = 0.f;
    for (int n = s; n < e; ++n) acc += b2f_lo((unsigned)h[(size_t)n * HID + t]);
    p[t] = acc / fmaxf((float)(e - s), 1.0f);
    __syncthreads();
    float a2 = bm1[t];
    for (int k = 0; k < HID; ++k) a2 = fmaf(p[k], Wm1[k * HID + t], a2);
    red[t] = fmaxf(a2, 0.f) * Wm2[t];
    __syncthreads();
    for (int o = 128; o > 0; o >>= 1) {
        if (t < o) red[t] += red[t + o];
        __syncthreads();
    }
    if (t == 0) out[g] = red[0] + bm2[0];
}

// ---------------- launch: 11 dispatches ----------------
extern "C" void kernel_launch(void* const* d_in, const int* in_sizes, int n_in,
                              void* d_out, int out_size, void* d_ws, size_t ws_size,
                              hipStream_t stream) {
    const float* x    = (const float*)d_in[0];
    const int*   ei   = (const int*)d_in[1];
    const int*   batch= (const int*)d_in[2];
    const float* W0   = (const float*)d_in[3];
    const float* b0   = (const float*)d_in[4];
    const float* W1   = (const float*)d_in[5];
    const float* b1   = (const float*)d_in[6];
    const float* W2   = (const float*)d_in[7];
    const float* b2   = (const float*)d_in[8];
    const float* Wm1  = (const float*)d_in[9];
    const float* bm1  = (const float*)d_in[10];
    const float* Wm2  = (const float*)d_in[11];
    const float* bm2  = (const float*)d_in[12];
    float* out = (float*)d_out;

    char* ws = (char*)d_ws;
    size_t off = 0;
    auto alloc = [&](size_t bytes) -> void* {
        void* p = ws + off;
        off += (bytes + 255) & ~(size_t)255;
        return p;
    };
    // deg + scan flags contiguous so ONE memset zeroes both
    int*      deg       = (int*)     alloc((size_t)(N_NODES + 64) * 4);
    unsigned* flags     = (unsigned*)(deg + N_NODES);
    float*    dis       = (float*)   alloc((size_t)N_NODES * 4);
    int*      row_start = (int*)     alloc((size_t)(N_NODES + 1) * 4);
    int*      cursor    = (int*)     alloc((size_t)N_NODES * 4);
    unsigned* csr       = (unsigned*)alloc((size_t)N_EDGES * 4);
    unsigned short* x_bf = (unsigned short*)alloc((size_t)N_NODES * F_IN * 2);
    unsigned short* Wt0  = (unsigned short*)alloc((size_t)F_IN * HID * 2);
    unsigned short* Wt1  = (unsigned short*)alloc((size_t)HID * HID * 2);
    unsigned short* Wt2  = (unsigned short*)alloc((size_t)HID * HID * 2);
    unsigned short* bufA = (unsigned short*)alloc((size_t)NPAD * HID * 2);
    unsigned short* h1   = (unsigned short*)alloc((size_t)NPAD * HID * 2);
    unsigned short* h2   = (unsigned short*)alloc((size_t)NPAD * HID * 2);

    const int* srcp = ei;
    const int* dstp = ei + N_EDGES;

    hipMemsetAsync(deg, 0, (size_t)(N_NODES + 64) * 4, stream);
    prep_kernel    <<<10015, 256, 0, stream>>>(dstp, deg, x, x_bf, W0, W1, W2, Wt0, Wt1, Wt2);
    scan_dis_kernel<<<49, 256, 0, stream>>>(deg, flags, dis, row_start, cursor);
    fill_csr       <<<(N_EDGES + 255) / 256, 256, 0, stream>>>(srcp, dstp, dis, cursor, csr);

    dim3 ggrid(NPAD / 128, 2);

    agg_bf16<F_IN><<<(N_NODES + 3) / 4, 256, 0, stream>>>(x_bf, row_start, csr, dis, bufA);
    gemm_direct<F_IN><<<ggrid, 256, 0, stream>>>(bufA, Wt0, b0, h1);

    agg_bf16<HID><<<(N_NODES + 3) / 4, 256, 0, stream>>>(h1, row_start, csr, dis, bufA);
    gemm_direct<HID><<<ggrid, 256, 0, stream>>>(bufA, Wt1, b1, h2);

    agg_bf16<HID><<<(N_NODES + 3) / 4, 256, 0, stream>>>(h2, row_start, csr, dis, bufA);
    gemm_direct<HID><<<ggrid, 256, 0, stream>>>(bufA, Wt2, b2, h1);

    pool_mlp_kernel<<<N_GRAPHS, 256, 0, stream>>>(h1, batch, Wm1, bm1, Wm2, bm2, out);
}